// Round 6
// baseline (333.827 us; speedup 1.0000x reference)
//
#include <hip/hip_runtime.h>
#include <hip/hip_bf16.h>

#define T_SEQ   2048
#define D_MODEL 1024
#define N_HEADS 16
#define HEAD_DIM 64
#define BT      8192   // B*T
#define N3D     3072

using short8  = __attribute__((ext_vector_type(8))) short;
using short4v = __attribute__((ext_vector_type(4))) short;
using floatx4 = __attribute__((ext_vector_type(4))) float;

#define QSCALE 0.18033688f  // 0.125 * log2(e): folded into Q at QKV epilogue

__device__ __forceinline__ unsigned short rne_bf16(float f) {
  unsigned int u = __float_as_uint(f);
  u = (u + 0x7fffu + ((u >> 16) & 1u)) >> 16;
  return (unsigned short)u;
}

// async global->LDS, 16B per lane; dest = wave-uniform base + lane*16 (m104)
__device__ __forceinline__ void gload_lds16(const unsigned short* g,
                                            unsigned short* l) {
  __builtin_amdgcn_global_load_lds(
      (const __attribute__((address_space(1))) void*)g,
      (__attribute__((address_space(3))) void*)l, 16, 0, 0);
}

// ---------------- elementwise fp32 -> bf16 ----------------
__global__ __launch_bounds__(256) void k_convert(const float* __restrict__ in,
                                                 unsigned short* __restrict__ out) {
  size_t i = ((size_t)blockIdx.x * 256 + threadIdx.x) * 8;
  float4 a = *(const float4*)(in + i);
  float4 b = *(const float4*)(in + i + 4);
  short8 v;
  v[0] = (short)rne_bf16(a.x); v[1] = (short)rne_bf16(a.y);
  v[2] = (short)rne_bf16(a.z); v[3] = (short)rne_bf16(a.w);
  v[4] = (short)rne_bf16(b.x); v[5] = (short)rne_bf16(b.y);
  v[6] = (short)rne_bf16(b.z); v[7] = (short)rne_bf16(b.w);
  *(short8*)(((short*)out) + i) = v;
}

// ------------- tiled transpose + convert -------------
__global__ __launch_bounds__(256) void k_transpose_convert(
    const float* __restrict__ in, unsigned short* __restrict__ out_hi,
    int R, int C) {
  __shared__ float tile[64][65];
  int tiles_c = C >> 6;
  int r0 = (blockIdx.x / tiles_c) << 6;
  int c0 = (blockIdx.x % tiles_c) << 6;
  int tid = threadIdx.x;
#pragma unroll
  for (int i = 0; i < 16; ++i) {
    int idx = tid + i * 256;
    int r = idx >> 6, c = idx & 63;
    tile[r][c] = in[(size_t)(r0 + r) * C + c0 + c];
  }
  __syncthreads();
#pragma unroll
  for (int i = 0; i < 16; ++i) {
    int idx = tid + i * 256;
    int orow = idx >> 6, oc = idx & 63;
    out_hi[(size_t)(c0 + orow) * R + r0 + oc] = rne_bf16(tile[oc][orow]);
  }
}

// ---------------- QKV GEMM (plain bf16 MFMA, global_load_lds staging) ------
__global__ __launch_bounds__(256) void k_qkv_gemm(
    const unsigned short* __restrict__ A, const unsigned short* __restrict__ Bt,
    const float* __restrict__ bias,
    unsigned short* __restrict__ Qo, unsigned short* __restrict__ Ko,
    unsigned short* __restrict__ Vt) {
  __shared__ __align__(16) unsigned short As[128 * 32];
  __shared__ __align__(16) unsigned short Bs[128 * 32];
  int tid = threadIdx.x;
  int m0 = (blockIdx.x / 24) * 128;
  int n0 = (blockIdx.x % 24) * 128;
  int w = tid >> 6, lane = tid & 63, quad = lane >> 4, l16 = lane & 15;
  int wm = (w >> 1) * 64, wn = (w & 1) * 64;
  floatx4 acc[4][4] = {};

  int s_row[2], s_sp[2];
#pragma unroll
  for (int i = 0; i < 2; ++i) {
    int u = tid + i * 256;
    s_row[i] = u >> 2;
    s_sp[i] = (u & 3) ^ ((s_row[i] >> 1) & 3);
  }
  int a_off[4], b_off[4];
#pragma unroll
  for (int t = 0; t < 4; ++t) {
    int ra = wm + t * 16 + l16, rb = wn + t * 16 + l16;
    a_off[t] = ra * 32 + (quad ^ ((ra >> 1) & 3)) * 8;
    b_off[t] = rb * 32 + (quad ^ ((rb >> 1) & 3)) * 8;
  }

  for (int k0 = 0; k0 < 1024; k0 += 32) {
#pragma unroll
    for (int i = 0; i < 2; ++i) {
      int ub = (tid & ~63) + i * 256;
      gload_lds16(A + (size_t)(m0 + s_row[i]) * 1024 + k0 + s_sp[i] * 8,
                  &As[ub * 8]);
      gload_lds16(Bt + (size_t)(n0 + s_row[i]) * 1024 + k0 + s_sp[i] * 8,
                  &Bs[ub * 8]);
    }
    __syncthreads();
    short8 af[4], bf[4];
#pragma unroll
    for (int mt = 0; mt < 4; ++mt) af[mt] = *(const short8*)(&As[a_off[mt]]);
#pragma unroll
    for (int nt = 0; nt < 4; ++nt) bf[nt] = *(const short8*)(&Bs[b_off[nt]]);
#pragma unroll
    for (int mt = 0; mt < 4; ++mt)
#pragma unroll
      for (int nt = 0; nt < 4; ++nt)
        acc[mt][nt] = __builtin_amdgcn_mfma_f32_16x16x32_bf16(af[mt], bf[nt],
                                                              acc[mt][nt], 0, 0, 0);
    __syncthreads();
  }

#pragma unroll
  for (int nt = 0; nt < 4; ++nt) {
    int n = n0 + wn + nt * 16 + l16;
    float bv = bias[n];
    int which = n >> 10;           // 0=Q 1=K 2=V
    int nn = n & 1023;
    int h = nn >> 6, hd = nn & 63;
#pragma unroll
    for (int mt = 0; mt < 4; ++mt) {
      int mbase = m0 + wm + mt * 16 + quad * 4;
      int b = mbase >> 11;
      int t0 = mbase & 2047;
      int head = b * N_HEADS + h;
      if (which == 2) {
        short4v vv;
#pragma unroll
        for (int r = 0; r < 4; ++r) vv[r] = (short)rne_bf16(acc[mt][nt][r] + bv);
        *(short4v*)(&Vt[((size_t)head * HEAD_DIM + hd) * T_SEQ + t0]) = vv;
      } else {
        unsigned short* dst = (which == 0) ? Qo : Ko;
        float scl = (which == 0) ? QSCALE : 1.0f;
#pragma unroll
        for (int r = 0; r < 4; ++r)
          dst[((size_t)head * T_SEQ + t0 + r) * HEAD_DIM + hd] =
              rne_bf16((acc[mt][nt][r] + bv) * scl);
      }
    }
  }
}

// ---------------- flash attention (128 q-rows/block, 32 q-rows/wave) -------
// Q pre-scaled by 0.125*log2e -> p = 2^s directly. Row sums via ones-MFMA.
// K/V frags read ONCE per wave and reused across both q-frags (R6: cuts
// LDS-read traffic per q-row 1.8x; R5 was LDS-read-pipe bound).
__global__ __launch_bounds__(256) void k_attn(
    const unsigned short* __restrict__ Q, const unsigned short* __restrict__ K,
    const unsigned short* __restrict__ Vt, unsigned short* __restrict__ Oo) {
  __shared__ __align__(16) unsigned short Klds[64 * 64];
  __shared__ __align__(16) unsigned short Vlds[64 * 64];
  __shared__ __align__(16) unsigned short Plds[4][2][16 * 64];
  int tid = threadIdx.x;
  int head = blockIdx.x >> 4;
  int qb = (blockIdx.x & 15) << 7;
  int b = head >> 4, h = head & 15;
  int w = tid >> 6, lane = tid & 63, quad = lane >> 4, l16 = lane & 15;
  const unsigned short* Qh = Q + (size_t)head * T_SEQ * HEAD_DIM;
  const unsigned short* Kh = K + (size_t)head * T_SEQ * HEAD_DIM;
  const unsigned short* Vh = Vt + (size_t)head * HEAD_DIM * T_SEQ;

  short8 qf[2][2];
#pragma unroll
  for (int qi = 0; qi < 2; ++qi) {
    int qrow = qb + w * 32 + qi * 16 + l16;
#pragma unroll
    for (int ks = 0; ks < 2; ++ks)
      qf[qi][ks] = *(const short8*)(Qh + (size_t)qrow * 64 + ks * 32 + quad * 8);
  }

  short8 ones;
#pragma unroll
  for (int j = 0; j < 8; ++j) ones[j] = (short)0x3F80;  // bf16 1.0

  floatx4 O[2][4] = {};
  floatx4 Osum[2] = {};
  const floatx4 zf = {};

  int sg[2], sidx[2], sub[2];
#pragma unroll
  for (int i = 0; i < 2; ++i) {
    sg[i] = (tid + i * 256) >> 6;         // wave-uniform
    sidx[i] = lane ^ sg[i];
    sub[i] = (tid & ~63) + i * 256;
  }

  for (int kb = 0; kb < 32; ++kb) {
#pragma unroll
    for (int i = 0; i < 2; ++i) {
      gload_lds16(Kh + ((size_t)(kb * 64 + sidx[i])) * 64 + sg[i] * 8,
                  &Klds[sub[i] * 8]);
      gload_lds16(Vh + (size_t)sidx[i] * T_SEQ + kb * 64 + sg[i] * 8,
                  &Vlds[sub[i] * 8]);
    }
    __syncthreads();

    // QK^T: K-frags read once, used for both q-frags
    floatx4 s[2][4];
#pragma unroll
    for (int ks = 0; ks < 2; ++ks) {
      int gk = ks * 4 + quad;
#pragma unroll
      for (int nt = 0; nt < 4; ++nt) {
        int PU = ((gk << 6) + nt * 16 + l16) ^ gk;
        short8 kf = *(const short8*)(&Klds[PU * 8]);
        if (ks == 0) {
          s[0][nt] = __builtin_amdgcn_mfma_f32_16x16x32_bf16(qf[0][0], kf, zf, 0, 0, 0);
          s[1][nt] = __builtin_amdgcn_mfma_f32_16x16x32_bf16(qf[1][0], kf, zf, 0, 0, 0);
        } else {
          s[0][nt] = __builtin_amdgcn_mfma_f32_16x16x32_bf16(qf[0][1], kf, s[0][nt], 0, 0, 0);
          s[1][nt] = __builtin_amdgcn_mfma_f32_16x16x32_bf16(qf[1][1], kf, s[1][nt], 0, 0, 0);
        }
      }
    }

    // p = 2^s, packed bf16 cvt, scatter into per-wave per-qfrag P region
#pragma unroll
    for (int qi = 0; qi < 2; ++qi) {
#pragma unroll
      for (int nt = 0; nt < 4; ++nt) {
        int key = nt * 16 + l16;
        int kg = key >> 3;
        int e = key & 7;
        int U0 = kg * 16 + quad * 4;
        float p0 = __builtin_amdgcn_exp2f(s[qi][nt][0]);
        float p1 = __builtin_amdgcn_exp2f(s[qi][nt][1]);
        float p2 = __builtin_amdgcn_exp2f(s[qi][nt][2]);
        float p3 = __builtin_amdgcn_exp2f(s[qi][nt][3]);
        __hip_bfloat162 lo2 = __float22bfloat162_rn(make_float2(p0, p1));
        __hip_bfloat162 hi2 = __float22bfloat162_rn(make_float2(p2, p3));
        unsigned int blo = *(unsigned int*)&lo2;
        unsigned int bhi = *(unsigned int*)&hi2;
        Plds[w][qi][((U0 + 0) ^ kg) * 8 + e] = (unsigned short)blo;
        Plds[w][qi][((U0 + 1) ^ kg) * 8 + e] = (unsigned short)(blo >> 16);
        Plds[w][qi][((U0 + 2) ^ kg) * 8 + e] = (unsigned short)bhi;
        Plds[w][qi][((U0 + 3) ^ kg) * 8 + e] = (unsigned short)(bhi >> 16);
      }
    }
    // Plds is per-wave: intra-wave ds ordering via lgkmcnt, no barrier.

    // PV: V-frags read once, used for both q-frags
#pragma unroll
    for (int ks = 0; ks < 2; ++ks) {
      int gk = ks * 4 + quad;
      int PUp = ((gk << 4) + l16) ^ gk;
      short8 pf0 = *(const short8*)(&Plds[w][0][PUp * 8]);
      short8 pf1 = *(const short8*)(&Plds[w][1][PUp * 8]);
      Osum[0] = __builtin_amdgcn_mfma_f32_16x16x32_bf16(pf0, ones, Osum[0], 0, 0, 0);
      Osum[1] = __builtin_amdgcn_mfma_f32_16x16x32_bf16(pf1, ones, Osum[1], 0, 0, 0);
#pragma unroll
      for (int dt = 0; dt < 4; ++dt) {
        int PUv = ((gk << 6) + dt * 16 + l16) ^ gk;
        short8 vf = *(const short8*)(&Vlds[PUv * 8]);
        O[0][dt] = __builtin_amdgcn_mfma_f32_16x16x32_bf16(pf0, vf, O[0][dt], 0, 0, 0);
        O[1][dt] = __builtin_amdgcn_mfma_f32_16x16x32_bf16(pf1, vf, O[1][dt], 0, 0, 0);
      }
    }
    __syncthreads();
  }

#pragma unroll
  for (int qi = 0; qi < 2; ++qi) {
    float inv[4];
#pragma unroll
    for (int r = 0; r < 4; ++r) inv[r] = 1.0f / Osum[qi][r];
#pragma unroll
    for (int dt = 0; dt < 4; ++dt)
#pragma unroll
      for (int r = 0; r < 4; ++r) {
        float val = O[qi][dt][r] * inv[r];
        int t = qb + w * 32 + qi * 16 + quad * 4 + r;
        size_t o = ((size_t)(b * T_SEQ + t)) * D_MODEL + h * HEAD_DIM + dt * 16 + l16;
        Oo[o] = rne_bf16(val);
      }
  }
}

// ---------------- proj GEMM (plain bf16, global_load_lds staging) ----------
__global__ __launch_bounds__(256) void k_proj_gemm(
    const unsigned short* __restrict__ A, const unsigned short* __restrict__ Bt,
    const float* __restrict__ bias, float* __restrict__ out) {
  __shared__ __align__(16) unsigned short As[128 * 32];
  __shared__ __align__(16) unsigned short Bs[128 * 32];
  int tid = threadIdx.x;
  int m0 = (blockIdx.x >> 3) * 128;
  int n0 = (blockIdx.x & 7) * 128;
  int w = tid >> 6, lane = tid & 63, quad = lane >> 4, l16 = lane & 15;
  int wm = (w >> 1) * 64, wn = (w & 1) * 64;
  floatx4 acc[4][4] = {};

  int s_row[2], s_sp[2];
#pragma unroll
  for (int i = 0; i < 2; ++i) {
    int u = tid + i * 256;
    s_row[i] = u >> 2;
    s_sp[i] = (u & 3) ^ ((s_row[i] >> 1) & 3);
  }
  int a_off[4], b_off[4];
#pragma unroll
  for (int t = 0; t < 4; ++t) {
    int ra = wm + t * 16 + l16, rb = wn + t * 16 + l16;
    a_off[t] = ra * 32 + (quad ^ ((ra >> 1) & 3)) * 8;
    b_off[t] = rb * 32 + (quad ^ ((rb >> 1) & 3)) * 8;
  }

  for (int k0 = 0; k0 < 1024; k0 += 32) {
#pragma unroll
    for (int i = 0; i < 2; ++i) {
      int ub = (tid & ~63) + i * 256;
      gload_lds16(A + (size_t)(m0 + s_row[i]) * 1024 + k0 + s_sp[i] * 8,
                  &As[ub * 8]);
      gload_lds16(Bt + (size_t)(n0 + s_row[i]) * 1024 + k0 + s_sp[i] * 8,
                  &Bs[ub * 8]);
    }
    __syncthreads();
    short8 af[4], bf[4];
#pragma unroll
    for (int mt = 0; mt < 4; ++mt) af[mt] = *(const short8*)(&As[a_off[mt]]);
#pragma unroll
    for (int nt = 0; nt < 4; ++nt) bf[nt] = *(const short8*)(&Bs[b_off[nt]]);
#pragma unroll
    for (int mt = 0; mt < 4; ++mt)
#pragma unroll
      for (int nt = 0; nt < 4; ++nt)
        acc[mt][nt] = __builtin_amdgcn_mfma_f32_16x16x32_bf16(af[mt], bf[nt],
                                                              acc[mt][nt], 0, 0, 0);
    __syncthreads();
  }

#pragma unroll
  for (int nt = 0; nt < 4; ++nt) {
    int n = n0 + wn + nt * 16 + l16;
    float bv = bias[n];
#pragma unroll
    for (int mt = 0; mt < 4; ++mt)
#pragma unroll
      for (int r = 0; r < 4; ++r) {
        int m = m0 + wm + mt * 16 + quad * 4 + r;
        out[(size_t)m * 1024 + n] = acc[mt][nt][r] + bv;
      }
  }
}

extern "C" void kernel_launch(void* const* d_in, const int* in_sizes, int n_in,
                              void* d_out, int out_size, void* d_ws, size_t ws_size,
                              hipStream_t stream) {
  const float* x     = (const float*)d_in[0];
  const float* wqkv  = (const float*)d_in[1];
  const float* bqkv  = (const float*)d_in[2];
  const float* wproj = (const float*)d_in[3];
  const float* bproj = (const float*)d_in[4];

  char* ws = (char*)d_ws;
  size_t off = 0;
  unsigned short* x_bf  = (unsigned short*)(ws + off); off += (size_t)BT * D_MODEL * 2;
  unsigned short* wq_T  = (unsigned short*)(ws + off); off += (size_t)N3D * D_MODEL * 2;
  unsigned short* wp_T  = (unsigned short*)(ws + off); off += (size_t)D_MODEL * D_MODEL * 2;
  unsigned short* Qb    = (unsigned short*)(ws + off); off += (size_t)BT * D_MODEL * 2;
  unsigned short* Kb    = (unsigned short*)(ws + off); off += (size_t)BT * D_MODEL * 2;
  unsigned short* Vt    = (unsigned short*)(ws + off); off += (size_t)BT * D_MODEL * 2;
  unsigned short* a_bf  = (unsigned short*)(ws + off); off += (size_t)BT * D_MODEL * 2;

  k_convert<<<(BT * D_MODEL) / (256 * 8), 256, 0, stream>>>(x, x_bf);
  k_transpose_convert<<<(1024 / 64) * (3072 / 64), 256, 0, stream>>>(wqkv, wq_T, 1024, 3072);
  k_transpose_convert<<<(1024 / 64) * (1024 / 64), 256, 0, stream>>>(wproj, wp_T, 1024, 1024);
  k_qkv_gemm<<<(BT / 128) * (N3D / 128), 256, 0, stream>>>(x_bf, wq_T, bqkv, Qb, Kb, Vt);
  // 64 heads x (T/128)=16 q-blocks = 1024 blocks
  k_attn<<<(T_SEQ / 128) * 4 * N_HEADS, 256, 0, stream>>>(Qb, Kb, Vt, a_bf);
  k_proj_gemm<<<(BT / 128) * (D_MODEL / 128), 256, 0, stream>>>(a_bf, wp_T, bproj, (float*)d_out);
}

// Round 7
// 325.363 us; speedup vs baseline: 1.0260x; 1.0260x over previous
//
#include <hip/hip_runtime.h>
#include <hip/hip_bf16.h>

#define T_SEQ   2048
#define D_MODEL 1024
#define N_HEADS 16
#define HEAD_DIM 64
#define BT      8192   // B*T
#define N3D     3072

using short8  = __attribute__((ext_vector_type(8))) short;
using short4v = __attribute__((ext_vector_type(4))) short;
using floatx4 = __attribute__((ext_vector_type(4))) float;

#define QSCALE 0.18033688f  // 0.125 * log2(e): folded into Q at QKV epilogue

__device__ __forceinline__ unsigned short rne_bf16(float f) {
  unsigned int u = __float_as_uint(f);
  u = (u + 0x7fffu + ((u >> 16) & 1u)) >> 16;
  return (unsigned short)u;
}

// async global->LDS, 16B per lane; dest = wave-uniform base + lane*16 (m104)
__device__ __forceinline__ void gload_lds16(const unsigned short* g,
                                            unsigned short* l) {
  __builtin_amdgcn_global_load_lds(
      (const __attribute__((address_space(1))) void*)g,
      (__attribute__((address_space(3))) void*)l, 16, 0, 0);
}

// ---------------- elementwise fp32 -> bf16 ----------------
__global__ __launch_bounds__(256) void k_convert(const float* __restrict__ in,
                                                 unsigned short* __restrict__ out) {
  size_t i = ((size_t)blockIdx.x * 256 + threadIdx.x) * 8;
  float4 a = *(const float4*)(in + i);
  float4 b = *(const float4*)(in + i + 4);
  short8 v;
  v[0] = (short)rne_bf16(a.x); v[1] = (short)rne_bf16(a.y);
  v[2] = (short)rne_bf16(a.z); v[3] = (short)rne_bf16(a.w);
  v[4] = (short)rne_bf16(b.x); v[5] = (short)rne_bf16(b.y);
  v[6] = (short)rne_bf16(b.z); v[7] = (short)rne_bf16(b.w);
  *(short8*)(((short*)out) + i) = v;
}

// ------------- tiled transpose + convert -------------
__global__ __launch_bounds__(256) void k_transpose_convert(
    const float* __restrict__ in, unsigned short* __restrict__ out_hi,
    int R, int C) {
  __shared__ float tile[64][65];
  int tiles_c = C >> 6;
  int r0 = (blockIdx.x / tiles_c) << 6;
  int c0 = (blockIdx.x % tiles_c) << 6;
  int tid = threadIdx.x;
#pragma unroll
  for (int i = 0; i < 16; ++i) {
    int idx = tid + i * 256;
    int r = idx >> 6, c = idx & 63;
    tile[r][c] = in[(size_t)(r0 + r) * C + c0 + c];
  }
  __syncthreads();
#pragma unroll
  for (int i = 0; i < 16; ++i) {
    int idx = tid + i * 256;
    int orow = idx >> 6, oc = idx & 63;
    out_hi[(size_t)(c0 + orow) * R + r0 + oc] = rne_bf16(tile[oc][orow]);
  }
}

// ---------------- QKV GEMM (plain bf16 MFMA, global_load_lds staging) ------
__global__ __launch_bounds__(256) void k_qkv_gemm(
    const unsigned short* __restrict__ A, const unsigned short* __restrict__ Bt,
    const float* __restrict__ bias,
    unsigned short* __restrict__ Qo, unsigned short* __restrict__ Ko,
    unsigned short* __restrict__ Vt) {
  __shared__ __align__(16) unsigned short As[128 * 32];
  __shared__ __align__(16) unsigned short Bs[128 * 32];
  int tid = threadIdx.x;
  int m0 = (blockIdx.x / 24) * 128;
  int n0 = (blockIdx.x % 24) * 128;
  int w = tid >> 6, lane = tid & 63, quad = lane >> 4, l16 = lane & 15;
  int wm = (w >> 1) * 64, wn = (w & 1) * 64;
  floatx4 acc[4][4] = {};

  int s_row[2], s_sp[2];
#pragma unroll
  for (int i = 0; i < 2; ++i) {
    int u = tid + i * 256;
    s_row[i] = u >> 2;
    s_sp[i] = (u & 3) ^ ((s_row[i] >> 1) & 3);
  }
  int a_off[4], b_off[4];
#pragma unroll
  for (int t = 0; t < 4; ++t) {
    int ra = wm + t * 16 + l16, rb = wn + t * 16 + l16;
    a_off[t] = ra * 32 + (quad ^ ((ra >> 1) & 3)) * 8;
    b_off[t] = rb * 32 + (quad ^ ((rb >> 1) & 3)) * 8;
  }

  for (int k0 = 0; k0 < 1024; k0 += 32) {
#pragma unroll
    for (int i = 0; i < 2; ++i) {
      int ub = (tid & ~63) + i * 256;
      gload_lds16(A + (size_t)(m0 + s_row[i]) * 1024 + k0 + s_sp[i] * 8,
                  &As[ub * 8]);
      gload_lds16(Bt + (size_t)(n0 + s_row[i]) * 1024 + k0 + s_sp[i] * 8,
                  &Bs[ub * 8]);
    }
    __syncthreads();
    short8 af[4], bf[4];
#pragma unroll
    for (int mt = 0; mt < 4; ++mt) af[mt] = *(const short8*)(&As[a_off[mt]]);
#pragma unroll
    for (int nt = 0; nt < 4; ++nt) bf[nt] = *(const short8*)(&Bs[b_off[nt]]);
#pragma unroll
    for (int mt = 0; mt < 4; ++mt)
#pragma unroll
      for (int nt = 0; nt < 4; ++nt)
        acc[mt][nt] = __builtin_amdgcn_mfma_f32_16x16x32_bf16(af[mt], bf[nt],
                                                              acc[mt][nt], 0, 0, 0);
    __syncthreads();
  }

#pragma unroll
  for (int nt = 0; nt < 4; ++nt) {
    int n = n0 + wn + nt * 16 + l16;
    float bv = bias[n];
    int which = n >> 10;           // 0=Q 1=K 2=V
    int nn = n & 1023;
    int h = nn >> 6, hd = nn & 63;
#pragma unroll
    for (int mt = 0; mt < 4; ++mt) {
      int mbase = m0 + wm + mt * 16 + quad * 4;
      int b = mbase >> 11;
      int t0 = mbase & 2047;
      int head = b * N_HEADS + h;
      if (which == 2) {
        short4v vv;
#pragma unroll
        for (int r = 0; r < 4; ++r) vv[r] = (short)rne_bf16(acc[mt][nt][r] + bv);
        *(short4v*)(&Vt[((size_t)head * HEAD_DIM + hd) * T_SEQ + t0]) = vv;
      } else {
        unsigned short* dst = (which == 0) ? Qo : Ko;
        float scl = (which == 0) ? QSCALE : 1.0f;
#pragma unroll
        for (int r = 0; r < 4; ++r)
          dst[((size_t)head * T_SEQ + t0 + r) * HEAD_DIM + hd] =
              rne_bf16((acc[mt][nt][r] + bv) * scl);
      }
    }
  }
}

// ---------------- flash attention (S^T form, register P-transpose) ---------
// R7: compute S^T = K·Q^T so exp2 output sits keyed-by-row in registers.
// Tile nt of the QK^T MFMA processes permuted keys
//   key(nt, m) = (nt>>1)*32 + (m>>2)*8 + (nt&1)*4 + (m&3)
// chosen so that the packed bf16 pairs ARE the PV B-fragment (P^T) with no
// cross-lane movement and no LDS round-trip. Permutation lives entirely in
// the K staging source index; Klds read addresses identical to R6 (0 confl).
// PV: A = V^T (staged in A-layout), D = O^T[d][q]. Row sums via ones-A MFMA
// (all-rows-equal -> l[q] in every reg; single rcp). Arithmetic bitwise
// identical to R6.
__global__ __launch_bounds__(256) void k_attn(
    const unsigned short* __restrict__ Q, const unsigned short* __restrict__ K,
    const unsigned short* __restrict__ Vt, unsigned short* __restrict__ Oo) {
  __shared__ __align__(16) unsigned short Klds[64 * 64];
  __shared__ __align__(16) unsigned short Vlds[64 * 64];
  int tid = threadIdx.x;
  int head = blockIdx.x >> 4;
  int qb = (blockIdx.x & 15) << 7;
  int b = head >> 4, h = head & 15;
  int w = tid >> 6, lane = tid & 63, quad = lane >> 4, l16 = lane & 15;
  const unsigned short* Qh = Q + (size_t)head * T_SEQ * HEAD_DIM;
  const unsigned short* Kh = K + (size_t)head * T_SEQ * HEAD_DIM;
  const unsigned short* Vh = Vt + (size_t)head * HEAD_DIM * T_SEQ;

  // Q B-frag: lane n=q=l16 holds d-elems quad*8+j (+32 per ks-half)
  short8 qf[2][2];
#pragma unroll
  for (int qi = 0; qi < 2; ++qi) {
    int qrow = qb + w * 32 + qi * 16 + l16;
#pragma unroll
    for (int ks = 0; ks < 2; ++ks)
      qf[qi][ks] = *(const short8*)(Qh + (size_t)qrow * 64 + ks * 32 + quad * 8);
  }

  short8 ones;
#pragma unroll
  for (int j = 0; j < 8; ++j) ones[j] = (short)0x3F80;  // bf16 1.0

  floatx4 O[2][4] = {};
  floatx4 Osum[2] = {};
  const floatx4 zf = {};

  // staging invariants. LDS slot unit = tid + i*256; stored logical index
  // xs = lane ^ sg. K source row applies the tile permutation to xs.
  int sg[2], sub[2], ksrc[2], vsrc[2];
#pragma unroll
  for (int i = 0; i < 2; ++i) {
    sg[i] = (tid + i * 256) >> 6;         // wave-uniform
    sub[i] = (tid & ~63) + i * 256;
    int xs = lane ^ sg[i];
    int ntp = xs >> 4, mp = xs & 15;
    ksrc[i] = ((ntp >> 1) << 5) + ((mp >> 2) << 3) + ((ntp & 1) << 2) + (mp & 3);
    vsrc[i] = xs;                          // V^T row d
  }

  for (int kb = 0; kb < 32; ++kb) {
#pragma unroll
    for (int i = 0; i < 2; ++i) {
      gload_lds16(Kh + ((size_t)(kb * 64 + ksrc[i])) * 64 + sg[i] * 8,
                  &Klds[sub[i] * 8]);
      gload_lds16(Vh + (size_t)vsrc[i] * T_SEQ + kb * 64 + sg[i] * 8,
                  &Vlds[sub[i] * 8]);
    }
    __syncthreads();

    // S^T = K·Q^T (K-frags read once, shared across both q-frags)
    floatx4 s[2][4];
#pragma unroll
    for (int ks = 0; ks < 2; ++ks) {
      int gk = ks * 4 + quad;
#pragma unroll
      for (int nt = 0; nt < 4; ++nt) {
        int PU = ((gk << 6) + nt * 16 + l16) ^ gk;
        short8 kf = *(const short8*)(&Klds[PU * 8]);
        if (ks == 0) {
          s[0][nt] = __builtin_amdgcn_mfma_f32_16x16x32_bf16(kf, qf[0][0], zf, 0, 0, 0);
          s[1][nt] = __builtin_amdgcn_mfma_f32_16x16x32_bf16(kf, qf[1][0], zf, 0, 0, 0);
        } else {
          s[0][nt] = __builtin_amdgcn_mfma_f32_16x16x32_bf16(kf, qf[0][1], s[0][nt], 0, 0, 0);
          s[1][nt] = __builtin_amdgcn_mfma_f32_16x16x32_bf16(kf, qf[1][1], s[1][nt], 0, 0, 0);
        }
      }
    }

    // p = 2^s, pack to bf16 pairs -> directly the P^T B-frags
    short8 pB[2][2];
#pragma unroll
    for (int qi = 0; qi < 2; ++qi) {
      unsigned int dw[4][2];
#pragma unroll
      for (int nt = 0; nt < 4; ++nt) {
        float p0 = __builtin_amdgcn_exp2f(s[qi][nt][0]);
        float p1 = __builtin_amdgcn_exp2f(s[qi][nt][1]);
        float p2 = __builtin_amdgcn_exp2f(s[qi][nt][2]);
        float p3 = __builtin_amdgcn_exp2f(s[qi][nt][3]);
        __hip_bfloat162 lo2 = __float22bfloat162_rn(make_float2(p0, p1));
        __hip_bfloat162 hi2 = __float22bfloat162_rn(make_float2(p2, p3));
        dw[nt][0] = *(unsigned int*)&lo2;
        dw[nt][1] = *(unsigned int*)&hi2;
      }
#pragma unroll
      for (int ks = 0; ks < 2; ++ks) {
        union { unsigned int u[4]; short8 s8; } cv;
        cv.u[0] = dw[2 * ks][0];
        cv.u[1] = dw[2 * ks][1];
        cv.u[2] = dw[2 * ks + 1][0];
        cv.u[3] = dw[2 * ks + 1][1];
        pB[qi][ks] = cv.s8;
      }
    }

    // PV: O^T += V^T · P^T ; row sums via ones-A MFMA
#pragma unroll
    for (int ks = 0; ks < 2; ++ks) {
      int gk = ks * 4 + quad;
      Osum[0] = __builtin_amdgcn_mfma_f32_16x16x32_bf16(ones, pB[0][ks], Osum[0], 0, 0, 0);
      Osum[1] = __builtin_amdgcn_mfma_f32_16x16x32_bf16(ones, pB[1][ks], Osum[1], 0, 0, 0);
#pragma unroll
      for (int dt = 0; dt < 4; ++dt) {
        int PUv = ((gk << 6) + dt * 16 + l16) ^ gk;
        short8 vf = *(const short8*)(&Vlds[PUv * 8]);
        O[0][dt] = __builtin_amdgcn_mfma_f32_16x16x32_bf16(vf, pB[0][ks], O[0][dt], 0, 0, 0);
        O[1][dt] = __builtin_amdgcn_mfma_f32_16x16x32_bf16(vf, pB[1][ks], O[1][dt], 0, 0, 0);
      }
    }
    __syncthreads();
  }

  // O^T layout: lane col q=l16, rows d = dt*16 + quad*4 + r -> b64 stores
#pragma unroll
  for (int qi = 0; qi < 2; ++qi) {
    float inv = 1.0f / Osum[qi][0];
    int t = qb + w * 32 + qi * 16 + l16;
    size_t rowo = ((size_t)(b * T_SEQ + t)) * D_MODEL + h * HEAD_DIM;
#pragma unroll
    for (int dt = 0; dt < 4; ++dt) {
      short4v ov;
#pragma unroll
      for (int r = 0; r < 4; ++r) ov[r] = (short)rne_bf16(O[qi][dt][r] * inv);
      *(short4v*)(&Oo[rowo + dt * 16 + quad * 4]) = ov;
    }
  }
}

// ---------------- proj GEMM (plain bf16, global_load_lds staging) ----------
__global__ __launch_bounds__(256) void k_proj_gemm(
    const unsigned short* __restrict__ A, const unsigned short* __restrict__ Bt,
    const float* __restrict__ bias, float* __restrict__ out) {
  __shared__ __align__(16) unsigned short As[128 * 32];
  __shared__ __align__(16) unsigned short Bs[128 * 32];
  int tid = threadIdx.x;
  int m0 = (blockIdx.x >> 3) * 128;
  int n0 = (blockIdx.x & 7) * 128;
  int w = tid >> 6, lane = tid & 63, quad = lane >> 4, l16 = lane & 15;
  int wm = (w >> 1) * 64, wn = (w & 1) * 64;
  floatx4 acc[4][4] = {};

  int s_row[2], s_sp[2];
#pragma unroll
  for (int i = 0; i < 2; ++i) {
    int u = tid + i * 256;
    s_row[i] = u >> 2;
    s_sp[i] = (u & 3) ^ ((s_row[i] >> 1) & 3);
  }
  int a_off[4], b_off[4];
#pragma unroll
  for (int t = 0; t < 4; ++t) {
    int ra = wm + t * 16 + l16, rb = wn + t * 16 + l16;
    a_off[t] = ra * 32 + (quad ^ ((ra >> 1) & 3)) * 8;
    b_off[t] = rb * 32 + (quad ^ ((rb >> 1) & 3)) * 8;
  }

  for (int k0 = 0; k0 < 1024; k0 += 32) {
#pragma unroll
    for (int i = 0; i < 2; ++i) {
      int ub = (tid & ~63) + i * 256;
      gload_lds16(A + (size_t)(m0 + s_row[i]) * 1024 + k0 + s_sp[i] * 8,
                  &As[ub * 8]);
      gload_lds16(Bt + (size_t)(n0 + s_row[i]) * 1024 + k0 + s_sp[i] * 8,
                  &Bs[ub * 8]);
    }
    __syncthreads();
    short8 af[4], bf[4];
#pragma unroll
    for (int mt = 0; mt < 4; ++mt) af[mt] = *(const short8*)(&As[a_off[mt]]);
#pragma unroll
    for (int nt = 0; nt < 4; ++nt) bf[nt] = *(const short8*)(&Bs[b_off[nt]]);
#pragma unroll
    for (int mt = 0; mt < 4; ++mt)
#pragma unroll
      for (int nt = 0; nt < 4; ++nt)
        acc[mt][nt] = __builtin_amdgcn_mfma_f32_16x16x32_bf16(af[mt], bf[nt],
                                                              acc[mt][nt], 0, 0, 0);
    __syncthreads();
  }

#pragma unroll
  for (int nt = 0; nt < 4; ++nt) {
    int n = n0 + wn + nt * 16 + l16;
    float bv = bias[n];
#pragma unroll
    for (int mt = 0; mt < 4; ++mt)
#pragma unroll
      for (int r = 0; r < 4; ++r) {
        int m = m0 + wm + mt * 16 + quad * 4 + r;
        out[(size_t)m * 1024 + n] = acc[mt][nt][r] + bv;
      }
  }
}

extern "C" void kernel_launch(void* const* d_in, const int* in_sizes, int n_in,
                              void* d_out, int out_size, void* d_ws, size_t ws_size,
                              hipStream_t stream) {
  const float* x     = (const float*)d_in[0];
  const float* wqkv  = (const float*)d_in[1];
  const float* bqkv  = (const float*)d_in[2];
  const float* wproj = (const float*)d_in[3];
  const float* bproj = (const float*)d_in[4];

  char* ws = (char*)d_ws;
  size_t off = 0;
  unsigned short* x_bf  = (unsigned short*)(ws + off); off += (size_t)BT * D_MODEL * 2;
  unsigned short* wq_T  = (unsigned short*)(ws + off); off += (size_t)N3D * D_MODEL * 2;
  unsigned short* wp_T  = (unsigned short*)(ws + off); off += (size_t)D_MODEL * D_MODEL * 2;
  unsigned short* Qb    = (unsigned short*)(ws + off); off += (size_t)BT * D_MODEL * 2;
  unsigned short* Kb    = (unsigned short*)(ws + off); off += (size_t)BT * D_MODEL * 2;
  unsigned short* Vt    = (unsigned short*)(ws + off); off += (size_t)BT * D_MODEL * 2;
  unsigned short* a_bf  = (unsigned short*)(ws + off); off += (size_t)BT * D_MODEL * 2;

  k_convert<<<(BT * D_MODEL) / (256 * 8), 256, 0, stream>>>(x, x_bf);
  k_transpose_convert<<<(1024 / 64) * (3072 / 64), 256, 0, stream>>>(wqkv, wq_T, 1024, 3072);
  k_transpose_convert<<<(1024 / 64) * (1024 / 64), 256, 0, stream>>>(wproj, wp_T, 1024, 1024);
  k_qkv_gemm<<<(BT / 128) * (N3D / 128), 256, 0, stream>>>(x_bf, wq_T, bqkv, Qb, Kb, Vt);
  // 64 heads x (T/128)=16 q-blocks = 1024 blocks
  k_attn<<<(T_SEQ / 128) * 4 * N_HEADS, 256, 0, stream>>>(Qb, Kb, Vt, a_bf);
  k_proj_gemm<<<(BT / 128) * (D_MODEL / 128), 256, 0, stream>>>(a_bf, wp_T, bproj, (float*)d_out);
}